// Round 1
// baseline (519.698 us; speedup 1.0000x reference)
//
#include <hip/hip_runtime.h>
#include <math.h>

#define B_    8
#define CIN_  64
#define COUT_ 64
#define Hs    96
#define Ws    96
#define KK    9
#define PLANE (Hs*Ws)        // 9216
#define IMG   (CIN_*PLANE)   // 589824
#define NP    (B_*PLANE)     // 73728

// Transpose weights for contiguous scalar-load access:
//   wT[(k*64+c)*64+o]  = weight[o*576 + c*9 + k]   (36864 floats)
//   woT[(c*27+ch)*9+t] = w_off[ch*576 + c*9 + t]   (15552 floats)
__global__ void transpose_weights(const float* __restrict__ weight,
                                  const float* __restrict__ w_off,
                                  float* __restrict__ wT,
                                  float* __restrict__ woT) {
    int i = blockIdx.x * 256 + threadIdx.x;
    if (i < COUT_ * CIN_ * KK) {
        int o = i & 63;
        int c = (i >> 6) & 63;
        int k = i >> 12;
        wT[i] = weight[o * 576 + c * 9 + k];
    }
    if (i < 27 * CIN_ * KK) {
        int t  = i % 9;
        int ch = (i / 9) % 27;
        int c  = i / (27 * 9);
        woT[i] = w_off[ch * 576 + c * 9 + t];
    }
}

__global__ __launch_bounds__(256)
void deform_fused(const float* __restrict__ x,
                  const float* __restrict__ woT,
                  const float* __restrict__ b_off,
                  const float* __restrict__ wT,
                  const float* __restrict__ bias,
                  float* __restrict__ out) {
    int p = blockIdx.x * 256 + threadIdx.x;   // pixel index, grid exactly covers NP
    int b = p / PLANE;
    int r = p - b * PLANE;
    int h = r / Ws;
    int w = r - h * Ws;
    const float* xb = x + b * IMG;

    // ---------------- Phase 1: offset conv (64 -> 27), pad=1 ----------------
    float om[27];
#pragma unroll
    for (int ch = 0; ch < 27; ++ch) om[ch] = b_off[ch];

#pragma unroll 1
    for (int c = 0; c < CIN_; ++c) {
        const float* xp = xb + c * PLANE;
        float xv[9];
#pragma unroll
        for (int i = 0; i < 3; ++i) {
            int yy = h - 1 + i;
            bool vy = (yy >= 0) && (yy < Hs);
#pragma unroll
            for (int j = 0; j < 3; ++j) {
                int xx = w - 1 + j;
                bool v = vy && (xx >= 0) && (xx < Ws);
                xv[i * 3 + j] = v ? xp[yy * Ws + xx] : 0.f;
            }
        }
        const float* wc = woT + c * 243;   // contiguous, loop-uniform -> s_loads
#pragma unroll
        for (int ch = 0; ch < 27; ++ch) {
#pragma unroll
            for (int t = 0; t < 9; ++t)
                om[ch] = fmaf(xv[t], wc[ch * 9 + t], om[ch]);
        }
    }

    // ---------------- Phase 2: deformable sampling + main conv ----------------
    float acc[64];
#pragma unroll
    for (int o = 0; o < 64; ++o) acc[o] = bias[o];

#pragma unroll
    for (int k = 0; k < KK; ++k) {
        float dy = om[2 * k];
        float dx = om[2 * k + 1];
        float m  = 1.f / (1.f + expf(-om[18 + k]));

        float ys = (float)(h - 1 + k / 3) + dy;
        float xs = (float)(w - 1 + k % 3) + dx;

        float y0f = floorf(ys), x0f = floorf(xs);
        float ly = ys - y0f, lx = xs - x0f;
        float hy = 1.f - ly, hx = 1.f - lx;

        int y0 = (int)y0f, x0 = (int)x0f;
        int y1 = y0 + 1,  x1 = x0 + 1;
        bool vy0 = (y0 >= 0) && (y0 < Hs);
        bool vy1 = (y1 >= 0) && (y1 < Hs);
        bool vx0 = (x0 >= 0) && (x0 < Ws);
        bool vx1 = (x1 >= 0) && (x1 < Ws);

        float w00 = (vy0 && vx0) ? m * hy * hx : 0.f;
        float w01 = (vy0 && vx1) ? m * hy * lx : 0.f;
        float w10 = (vy1 && vx0) ? m * ly * hx : 0.f;
        float w11 = (vy1 && vx1) ? m * ly * lx : 0.f;

        int y0c = min(max(y0, 0), Hs - 1), y1c = min(max(y1, 0), Hs - 1);
        int x0c = min(max(x0, 0), Ws - 1), x1c = min(max(x1, 0), Ws - 1);
        int o00 = y0c * Ws + x0c, o01 = y0c * Ws + x1c;
        int o10 = y1c * Ws + x0c, o11 = y1c * Ws + x1c;

        const float* wk = wT + k * (CIN_ * COUT_);
#pragma unroll 1
        for (int c = 0; c < CIN_; ++c) {
            const float* xp = xb + c * PLANE;
            float v = xp[o00] * w00 + xp[o01] * w01 + xp[o10] * w10 + xp[o11] * w11;
            const float* wc = wk + c * COUT_;  // contiguous, loop-uniform -> s_load_dwordx16
#pragma unroll
            for (int o = 0; o < COUT_; ++o)
                acc[o] = fmaf(v, wc[o], acc[o]);
        }
    }

    int obase = b * (COUT_ * PLANE) + h * Ws + w;
#pragma unroll
    for (int o = 0; o < COUT_; ++o)
        out[obase + o * PLANE] = acc[o];
}

extern "C" void kernel_launch(void* const* d_in, const int* in_sizes, int n_in,
                              void* d_out, int out_size, void* d_ws, size_t ws_size,
                              hipStream_t stream) {
    const float* x      = (const float*)d_in[0];
    const float* w_off  = (const float*)d_in[1];
    const float* b_off  = (const float*)d_in[2];
    const float* weight = (const float*)d_in[3];
    const float* bias   = (const float*)d_in[4];
    float* out = (float*)d_out;

    char* ws = (char*)d_ws;
    float* wT  = (float*)ws;                 // 147456 B
    float* woT = (float*)(ws + 0x24000);     //  62208 B (ends < 0x34000)

    transpose_weights<<<144, 256, 0, stream>>>(weight, w_off, wT, woT);
    deform_fused<<<NP / 256, 256, 0, stream>>>(x, woT, b_off, wT, bias, out);
}